// Round 19
// baseline (94.692 us; speedup 1.0000x reference)
//
#include <hip/hip_runtime.h>
#include <math.h>

#define N 8192
#define D 256
#define BK 32
#define TILE 128
#define NB (N / TILE)       // 64 panels
#define NSTRIP 1056         // sum over bi of ceil((64-bi)/2); 1056 = 8*132

typedef _Float16 half8 __attribute__((ext_vector_type(8)));
typedef float f32x4 __attribute__((ext_vector_type(4)));

constexpr float MARGIN = 0.5f;
constexpr float EPS_F  = 1e-10f;

// ---------------------------------------------------------------------------
// async global->LDS, 16B per lane. LDS dest = wave-uniform base + lane*16.
// ---------------------------------------------------------------------------
__device__ inline void load_lds16(const void* g, void* l) {
    __builtin_amdgcn_global_load_lds(
        (const __attribute__((address_space(1))) void*)g,
        (__attribute__((address_space(3))) void*)l, 16, 0, 0);
}

// ---------------------------------------------------------------------------
// Fused prologue (one dispatch, 512 blocks x 256 thr): r16-verified verbatim.
// ---------------------------------------------------------------------------
__global__ void prep_kernel(const float* __restrict__ xs,
                            const int* __restrict__ ys_raw,
                            _Float16* __restrict__ x16, float* __restrict__ sq,
                            int* __restrict__ lbl, int* __restrict__ hist16,
                            float* __restrict__ sums, float* __restrict__ out) {
    const int tid = threadIdx.x;
    const int rb  = blockIdx.x;

    {
        const int r   = tid >> 4;
        const int c16 = tid & 15;
        const int row = rb * 16 + r;

        const float4* src = (const float4*)xs + (size_t)row * (D / 4) + c16 * 4;
        const float4 v0 = src[0], v1 = src[1], v2 = src[2], v3 = src[3];

        half8 h0 = { (_Float16)v0.x, (_Float16)v0.y, (_Float16)v0.z, (_Float16)v0.w,
                     (_Float16)v1.x, (_Float16)v1.y, (_Float16)v1.z, (_Float16)v1.w };
        half8 h1 = { (_Float16)v2.x, (_Float16)v2.y, (_Float16)v2.z, (_Float16)v2.w,
                     (_Float16)v3.x, (_Float16)v3.y, (_Float16)v3.z, (_Float16)v3.w };

        _Float16* dst = x16 + (size_t)row * D + c16 * 16;
        *(half8*)dst       = h0;
        *(half8*)(dst + 8) = h1;

        float s = v0.x*v0.x + v0.y*v0.y + v0.z*v0.z + v0.w*v0.w
                + v1.x*v1.x + v1.y*v1.y + v1.z*v1.z + v1.w*v1.w
                + v2.x*v2.x + v2.y*v2.y + v2.z*v2.z + v2.w*v2.w
                + v3.x*v3.x + v3.y*v3.y + v3.z*v3.z + v3.w*v3.w;
#pragma unroll
        for (int off = 1; off < 16; off <<= 1) s += __shfl_xor(s, off);
        if (c16 == 0) sq[row] = s;
    }

    if (rb < 16) {
        __shared__ int bad_s;
        __shared__ int lh[64];
        const int base = rb * 512;
        if (tid == 0) bad_s = 0;
        if (tid < 64) lh[tid] = 0;
        __syncthreads();
        int bad = 0;
        for (int i = tid; i < 512; i += 256) bad |= (ys_raw[2 * (base + i) + 1] != 0);
        if (bad) atomicOr(&bad_s, 1);
        __syncthreads();
        const bool is64 = (bad_s == 0);
        for (int i = tid; i < 512; i += 256) {
            const int v = is64 ? ys_raw[2 * (base + i)] : ys_raw[base + i];
            lbl[base + i] = v;
            atomicAdd(&lh[v & 63], 1);
        }
        __syncthreads();
        if (tid < 64) hist16[rb * 64 + tid] = lh[tid];
    }

    if (rb >= 16 && rb < 48) {
        const int base = (rb - 16) * 4096;
#pragma unroll
        for (int k = 0; k < 16; ++k) sums[base + k * 256 + tid] = 0.f;
    }
    if (rb == 48 && tid == 0) out[0] = 0.f;
}

// ---------------------------------------------------------------------------
// Epilogue math (r7/r10-verified), NO atomics: returns 6 floats.
// ---------------------------------------------------------------------------
struct EpiOut { float ca, cs, ra0, rs0, ra1, rs1; };

__device__ __forceinline__ EpiOut tile_epilogue(
    const f32x4 (&acc)[4][4], const float* __restrict__ sq,
    const int* __restrict__ lbl, const float (&sqj_)[4], const int (&yj_)[4],
    int rowbase, int colbase, bool diag, int cl, int g) {

    EpiOut o;
    float cs_all[4], cs_same[4];
#pragma unroll
    for (int nf = 0; nf < 4; ++nf) { cs_all[nf] = 0.f; cs_same[nf] = 0.f; }
    float rout_a[2], rout_s[2];

#pragma unroll
    for (int b = 0; b < 2; ++b) {
        float rs_all[8], rs_same[8];
#pragma unroll
        for (int e = 0; e < 8; ++e) { rs_all[e] = 0.f; rs_same[e] = 0.f; }

#pragma unroll
        for (int mh = 0; mh < 2; ++mh) {
            const int mf = 2 * b + mh;
#pragma unroll
            for (int r = 0; r < 4; ++r) {
                const int row   = rowbase + mf * 16 + g * 4 + r;
                const float sqi = sq[row];
                const int   yi  = lbl[row];
#pragma unroll
                for (int nf = 0; nf < 4; ++nf) {
                    float d2   = sqi + sqj_[nf] - 2.f * acc[mf][nf][r];
                    float dist = __builtin_amdgcn_sqrtf(fmaxf(d2, EPS_F));
                    if (diag) {
                        const int col = colbase + nf * 16 + cl;
                        if (row == col) dist = 1e-5f;   // exact diagonal sqrt(EPS)
                    }
                    const float dm = (yi == yj_[nf]) ? dist : 0.f;
                    cs_all[nf] += dist;
                    cs_same[nf] += dm;
                    rs_all[mh * 4 + r] += dist;
                    rs_same[mh * 4 + r] += dm;
                }
            }
        }

        // row butterfly: value-split 8 over 16 lanes + closing mask-1 stage
#define RSTEP(h, mask, bit)                                                     \
        {                                                                       \
            const bool hi = (cl >> (bit)) & 1;                                  \
            _Pragma("unroll")                                                   \
            for (int j = 0; j < (h); ++j) {                                     \
                float sa_ = hi ? rs_all[j] : rs_all[j + (h)];                   \
                float ka_ = hi ? rs_all[j + (h)] : rs_all[j];                   \
                rs_all[j] = ka_ + __shfl_xor(sa_, (mask));                      \
                float ss_ = hi ? rs_same[j] : rs_same[j + (h)];                 \
                float ks_ = hi ? rs_same[j + (h)] : rs_same[j];                 \
                rs_same[j] = ks_ + __shfl_xor(ss_, (mask));                     \
            }                                                                   \
        }
        RSTEP(4, 8, 3)
        RSTEP(2, 4, 2)
        RSTEP(1, 2, 1)
#undef RSTEP
        rs_all[0]  += __shfl_xor(rs_all[0], 1);
        rs_same[0] += __shfl_xor(rs_same[0], 1);
        rout_a[b] = rs_all[0];
        rout_s[b] = rs_same[0];
    }
    o.ra0 = rout_a[0]; o.rs0 = rout_s[0];
    o.ra1 = rout_a[1]; o.rs1 = rout_s[1];

    // col butterfly: value-split 4 over 4 g-lanes
    {
        const bool hi1 = (g >> 1) & 1;
#pragma unroll
        for (int j = 0; j < 2; ++j) {
            float sa_ = hi1 ? cs_all[j] : cs_all[j + 2];
            float ka_ = hi1 ? cs_all[j + 2] : cs_all[j];
            cs_all[j] = ka_ + __shfl_xor(sa_, 32);
            float ss_ = hi1 ? cs_same[j] : cs_same[j + 2];
            float ks_ = hi1 ? cs_same[j + 2] : cs_same[j];
            cs_same[j] = ks_ + __shfl_xor(ss_, 32);
        }
        const bool hi0 = g & 1;
        float sa_ = hi0 ? cs_all[0] : cs_all[1];
        float ka_ = hi0 ? cs_all[1] : cs_all[0];
        o.ca = ka_ + __shfl_xor(sa_, 16);
        float ss_ = hi0 ? cs_same[0] : cs_same[1];
        float ks_ = hi0 ? cs_same[1] : cs_same[0];
        o.cs = ks_ + __shfl_xor(ss_, 16);
    }
    return o;
}

__device__ __forceinline__ void fire_atomics(
    const EpiOut& o, float* __restrict__ sum_all, float* __restrict__ sum_same,
    int rowbase, int colbase, bool diag, int cl, int g) {
    if (!diag && !(cl & 1)) {
        const int e = cl >> 1;
        const int r0 = rowbase + (e >> 2) * 16 + g * 4 + (e & 3);
        atomicAdd(&sum_all[r0],  o.ra0);
        atomicAdd(&sum_same[r0], o.rs0);
        const int r1 = rowbase + (2 + (e >> 2)) * 16 + g * 4 + (e & 3);
        atomicAdd(&sum_all[r1],  o.ra1);
        atomicAdd(&sum_same[r1], o.rs1);
    }
    const int ccol = colbase + g * 16 + cl;
    atomicAdd(&sum_all[ccol],  o.ca);
    atomicAdd(&sum_same[ccol], o.cs);
}

// ---------------------------------------------------------------------------
// Strip pair kernel: one block = row-panel bi x 2 adjacent column panels
// (r12-verified strip decode), run through ONE continuous 16-iter single-
// barrier 3-buffer ring (r16-verified schedule, per-wave-exact vmcnt(4)).
// Tile-0's epilogue (VALU/DS only, atomics DEFERRED as 6 floats) runs
// between iters 7 and 8, overlapping tile-1's in-flight staging. All
// atomics fire after the final vmcnt(0) -> counted waits stay exact
// (mid-epilogue pure loads only make vmcnt(4) conservative).
// ---------------------------------------------------------------------------
__global__ __launch_bounds__(256, 3) void pair_kernel(
    const _Float16* __restrict__ x16, const int* __restrict__ lbl,
    const float* __restrict__ sq,
    float* __restrict__ sum_same8, float* __restrict__ sum_all8) {

    __shared__ _Float16 As[3][TILE * BK];   // 24 KB
    __shared__ _Float16 Bs[3][TILE * BK];   // 24 KB

    // ---- XCD-bijective swizzle (1056 % 8 == 0 -> exact chunking) ----
    const int xcd = blockIdx.x & 7;
    int rem = xcd * (NSTRIP / 8) + blockIdx.x / 8;
    float* __restrict__ sum_same = sum_same8 + (size_t)xcd * N;
    float* __restrict__ sum_all  = sum_all8  + (size_t)xcd * N;

    // ---- strip decode (r12-verified): bi, then bj0 = bi + 2*rem ----
    int bi = 0;
    for (;;) {
        const int ns = (65 - bi) >> 1;
        if (rem < ns) break;
        rem -= ns;
        ++bi;
    }
    const int bj0   = bi + 2 * rem;
    const int npan  = (bj0 == 63) ? 1 : 2;
    const bool diag0 = (bj0 == bi);          // tile 1 is never diagonal
    const int i0 = bi * TILE;

    const int tid  = threadIdx.x;
    const int w    = tid >> 6;
    const int lane = tid & 63;
    const int wm   = w >> 1;
    const int wn   = w & 1;
    const int cl   = lane & 15;
    const int g    = lane >> 4;

    const int rowbase  = i0 + wm * 64;
    const int colbase0 = bj0 * TILE + wn * 64;
    const int colbase1 = (bj0 + 1) * TILE + wn * 64;

    f32x4 acc[4][4];
#pragma unroll
    for (int a = 0; a < 4; ++a)
#pragma unroll
        for (int b = 0; b < 4; ++b) acc[a][b] = (f32x4){0.f, 0.f, 0.f, 0.f};

    // staging: 512 16B-chunks per tile; chunk c -> row=c>>2, kc=c&3
    const int c0 = w * 64 + lane;
    const int r0 = c0 >> 2, kc0 = c0 & 3;
    const int c1 = 256 + c0;
    const int r1 = c1 >> 2, kc1 = c1 & 3;

    // 4 global_load_lds per wave per stage -> vmcnt accounting exact
#define STAGE(buf, jbase, k0)                                                   \
    do {                                                                        \
        load_lds16(x16 + (size_t)(i0 + r0) * D + (k0) + kc0 * 8,                \
                   &As[buf][(size_t)(w * 64) * 8]);                             \
        load_lds16(x16 + (size_t)((jbase) + r0) * D + (k0) + kc0 * 8,           \
                   &Bs[buf][(size_t)(w * 64) * 8]);                             \
        load_lds16(x16 + (size_t)(i0 + r1) * D + (k0) + kc1 * 8,                \
                   &As[buf][(size_t)(256 + w * 64) * 8]);                       \
        load_lds16(x16 + (size_t)((jbase) + r1) * D + (k0) + kc1 * 8,           \
                   &Bs[buf][(size_t)(256 + w * 64) * 8]);                       \
    } while (0)

    STAGE(0, bj0 * TILE, 0);               // tiles 0,1 of panel 0 in flight
    STAGE(1, bj0 * TILE, BK);

    float sqj_[4];
    int   yj_[4];
    EpiOut ep0;

    // ================= first 8 iters: tile 0 (panel bj0) =================
#pragma unroll
    for (int t8 = 0; t8 < 8; ++t8) {
        const int cur = t8 % 3;

        if (t8 < 7)          asm volatile("s_waitcnt vmcnt(4)" ::: "memory");
        else if (npan == 2)  asm volatile("s_waitcnt vmcnt(4)" ::: "memory");
        else                 asm volatile("s_waitcnt vmcnt(0)" ::: "memory");
        __builtin_amdgcn_s_barrier();      // tile t8 landed AND buf (t8-1)%3 free

        // stage u = t8+2 (u<=7: panel 0; u=8,9: panel 1's k=0,32 if present)
        if (t8 < 6) {
            STAGE((t8 + 2) % 3, bj0 * TILE, (t8 + 2) * BK);
        } else if (npan == 2) {
            STAGE((t8 + 2) % 3, (bj0 + 1) * TILE, (t8 - 6) * BK);
        }

        if (t8 == 7) {                     // hoist tile-0 epilogue operands
#pragma unroll
            for (int nf = 0; nf < 4; ++nf) {
                const int c = colbase0 + nf * 16 + cl;
                sqj_[nf] = sq[c];
                yj_[nf]  = lbl[c];
            }
        }

        half8 af[4], bf[4];
#pragma unroll
        for (int mf = 0; mf < 4; ++mf)
            af[mf] = *(const half8*)&As[cur][(wm * 64 + mf * 16 + cl) * BK + g * 8];
#pragma unroll
        for (int nf = 0; nf < 4; ++nf)
            bf[nf] = *(const half8*)&Bs[cur][(wn * 64 + nf * 16 + cl) * BK + g * 8];

        __builtin_amdgcn_s_setprio(1);
#pragma unroll
        for (int mf = 0; mf < 4; ++mf)
#pragma unroll
            for (int nf = 0; nf < 4; ++nf)
                acc[mf][nf] = __builtin_amdgcn_mfma_f32_16x16x32_f16(
                    af[mf], bf[nf], acc[mf][nf], 0, 0, 0);
        __builtin_amdgcn_s_setprio(0);
    }

    if (npan == 1) {
        // single-panel strip: immediate epilogue + atomics (r16 behavior)
        ep0 = tile_epilogue(acc, sq, lbl, sqj_, yj_, rowbase, colbase0, diag0, cl, g);
        fire_atomics(ep0, sum_all, sum_same, rowbase, colbase0, diag0, cl, g);
        return;
    }

    // ---- mid-epilogue for tile 0: pure loads + VALU/shfl only; atomics
    // deferred (6 floats). Runs while tile-1's staged loads are in flight.
    ep0 = tile_epilogue(acc, sq, lbl, sqj_, yj_, rowbase, colbase0, diag0, cl, g);

#pragma unroll
    for (int a = 0; a < 4; ++a)
#pragma unroll
        for (int b = 0; b < 4; ++b) acc[a][b] = (f32x4){0.f, 0.f, 0.f, 0.f};

    // ================= second 8 iters: tile 1 (panel bj0+1) ==============
#pragma unroll
    for (int ks = 0; ks < 8; ++ks) {
        const int cur = (ks + 2) % 3;      // global iter = ks+8

        if (ks < 7) asm volatile("s_waitcnt vmcnt(4)" ::: "memory");
        else        asm volatile("s_waitcnt vmcnt(0)" ::: "memory");
        __builtin_amdgcn_s_barrier();

        if (ks < 6) STAGE((ks + 1) % 3, (bj0 + 1) * TILE, (ks + 2) * BK); // u=ks+10

        if (ks == 7) {                     // hoist tile-1 epilogue operands
#pragma unroll
            for (int nf = 0; nf < 4; ++nf) {
                const int c = colbase1 + nf * 16 + cl;
                sqj_[nf] = sq[c];
                yj_[nf]  = lbl[c];
            }
        }

        half8 af[4], bf[4];
#pragma unroll
        for (int mf = 0; mf < 4; ++mf)
            af[mf] = *(const half8*)&As[cur][(wm * 64 + mf * 16 + cl) * BK + g * 8];
#pragma unroll
        for (int nf = 0; nf < 4; ++nf)
            bf[nf] = *(const half8*)&Bs[cur][(wn * 64 + nf * 16 + cl) * BK + g * 8];

        __builtin_amdgcn_s_setprio(1);
#pragma unroll
        for (int mf = 0; mf < 4; ++mf)
#pragma unroll
            for (int nf = 0; nf < 4; ++nf)
                acc[mf][nf] = __builtin_amdgcn_mfma_f32_16x16x32_f16(
                    af[mf], bf[nf], acc[mf][nf], 0, 0, 0);
        __builtin_amdgcn_s_setprio(0);
    }
#undef STAGE

    // tile-1 epilogue (immediate) + deferred tile-0 atomics — all after drain
    EpiOut ep1 = tile_epilogue(acc, sq, lbl, sqj_, yj_, rowbase, colbase1, false, cl, g);
    fire_atomics(ep1, sum_all, sum_same, rowbase, colbase1, false, cl, g);
    fire_atomics(ep0, sum_all, sum_same, rowbase, colbase0, diag0, cl, g);
}

// ---------------------------------------------------------------------------
// Finalize: 32 blocks x 256 thr, one row per thread (r16-verified verbatim).
// ---------------------------------------------------------------------------
__global__ void finalize_kernel(const float* __restrict__ sum_same8,
                                const float* __restrict__ sum_all8,
                                const int* __restrict__ lbl,
                                const int* __restrict__ hist16,
                                float* __restrict__ out) {
    __shared__ int lh[64];
    __shared__ float wsums[4];
    const int tid = threadIdx.x;
    if (tid < 64) {
        int h = 0;
#pragma unroll
        for (int b = 0; b < 16; ++b) h += hist16[b * 64 + tid];
        lh[tid] = h;
    }
    __syncthreads();

    const int row = blockIdx.x * 256 + tid;
    float ss = 0.f, sa = 0.f;
#pragma unroll
    for (int x = 0; x < 8; ++x) {
        ss += sum_same8[(size_t)x * N + row];
        sa += sum_all8[(size_t)x * N + row];
    }

    const float cnt = (float)lh[lbl[row]];
    const float ap  = ss / cnt;
    const float an  = (sa - ss) / ((float)N - cnt);
    float local = fmaxf(ap - an + MARGIN, 0.f);

#pragma unroll
    for (int off = 32; off > 0; off >>= 1) local += __shfl_down(local, off);
    const int lane = tid & 63, wave = tid >> 6;
    if (lane == 0) wsums[wave] = local;
    __syncthreads();
    if (tid == 0)
        atomicAdd(out, (wsums[0] + wsums[1] + wsums[2] + wsums[3]) / (float)N);
}

// ---------------------------------------------------------------------------
extern "C" void kernel_launch(void* const* d_in, const int* in_sizes, int n_in,
                              void* d_out, int out_size, void* d_ws, size_t ws_size,
                              hipStream_t stream) {
    const float* xs     = (const float*)d_in[0];
    const int*   ys_raw = (const int*)d_in[1];

    float* ws        = (float*)d_ws;
    float* sum_same8 = ws;                         // [8][N]
    float* sum_all8  = ws + 8 * N;                 // [8][N]
    float* sqv       = ws + 16 * N;                // [N]
    int*   lbl       = (int*)(ws + 17 * N);        // [N]
    int*   hist16    = (int*)(ws + 18 * N);        // [16*64]
    _Float16* x16    = (_Float16*)(ws + 18 * N + 1024);  // [N*D] fp16 (4 MB)

    prep_kernel<<<N / 16, 256, 0, stream>>>(xs, ys_raw, x16, sqv, lbl, hist16,
                                            sum_same8, (float*)d_out);

    pair_kernel<<<NSTRIP, 256, 0, stream>>>(x16, lbl, sqv, sum_same8, sum_all8);

    finalize_kernel<<<32, 256, 0, stream>>>(sum_same8, sum_all8, lbl, hist16,
                                            (float*)d_out);
}

// Round 20
// 50.301 us; speedup vs baseline: 1.8825x; 1.8825x over previous
//
#include <hip/hip_runtime.h>
#include <math.h>

#define N 8192
#define D 256
#define BK 32
#define TILE 128
#define NB (N / TILE)              // 64 panels
#define NBLK (NB * (NB + 1) / 2)   // 2080 upper-triangular blocks
#define PGRID 768                  // persistent grid: 256 CU x 3 blocks/CU

typedef _Float16 half8 __attribute__((ext_vector_type(8)));
typedef float f32x4 __attribute__((ext_vector_type(4)));

constexpr float MARGIN = 0.5f;
constexpr float EPS_F  = 1e-10f;

// ---------------------------------------------------------------------------
// async global->LDS, 16B per lane. LDS dest = wave-uniform base + lane*16.
// ---------------------------------------------------------------------------
__device__ inline void load_lds16(const void* g, void* l) {
    __builtin_amdgcn_global_load_lds(
        (const __attribute__((address_space(1))) void*)g,
        (__attribute__((address_space(3))) void*)l, 16, 0, 0);
}

// ---------------------------------------------------------------------------
// Fused prologue (one dispatch, 512 blocks x 256 thr): r16-verified verbatim.
// ---------------------------------------------------------------------------
__global__ void prep_kernel(const float* __restrict__ xs,
                            const int* __restrict__ ys_raw,
                            _Float16* __restrict__ x16, float* __restrict__ sq,
                            int* __restrict__ lbl, int* __restrict__ hist16,
                            float* __restrict__ sums, float* __restrict__ out) {
    const int tid = threadIdx.x;
    const int rb  = blockIdx.x;

    {
        const int r   = tid >> 4;
        const int c16 = tid & 15;
        const int row = rb * 16 + r;

        const float4* src = (const float4*)xs + (size_t)row * (D / 4) + c16 * 4;
        const float4 v0 = src[0], v1 = src[1], v2 = src[2], v3 = src[3];

        half8 h0 = { (_Float16)v0.x, (_Float16)v0.y, (_Float16)v0.z, (_Float16)v0.w,
                     (_Float16)v1.x, (_Float16)v1.y, (_Float16)v1.z, (_Float16)v1.w };
        half8 h1 = { (_Float16)v2.x, (_Float16)v2.y, (_Float16)v2.z, (_Float16)v2.w,
                     (_Float16)v3.x, (_Float16)v3.y, (_Float16)v3.z, (_Float16)v3.w };

        _Float16* dst = x16 + (size_t)row * D + c16 * 16;
        *(half8*)dst       = h0;
        *(half8*)(dst + 8) = h1;

        float s = v0.x*v0.x + v0.y*v0.y + v0.z*v0.z + v0.w*v0.w
                + v1.x*v1.x + v1.y*v1.y + v1.z*v1.z + v1.w*v1.w
                + v2.x*v2.x + v2.y*v2.y + v2.z*v2.z + v2.w*v2.w
                + v3.x*v3.x + v3.y*v3.y + v3.z*v3.z + v3.w*v3.w;
#pragma unroll
        for (int off = 1; off < 16; off <<= 1) s += __shfl_xor(s, off);
        if (c16 == 0) sq[row] = s;
    }

    if (rb < 16) {
        __shared__ int bad_s;
        __shared__ int lh[64];
        const int base = rb * 512;
        if (tid == 0) bad_s = 0;
        if (tid < 64) lh[tid] = 0;
        __syncthreads();
        int bad = 0;
        for (int i = tid; i < 512; i += 256) bad |= (ys_raw[2 * (base + i) + 1] != 0);
        if (bad) atomicOr(&bad_s, 1);
        __syncthreads();
        const bool is64 = (bad_s == 0);
        for (int i = tid; i < 512; i += 256) {
            const int v = is64 ? ys_raw[2 * (base + i)] : ys_raw[base + i];
            lbl[base + i] = v;
            atomicAdd(&lh[v & 63], 1);
        }
        __syncthreads();
        if (tid < 64) hist16[rb * 64 + tid] = lh[tid];
    }

    if (rb >= 16 && rb < 48) {
        const int base = (rb - 16) * 4096;
#pragma unroll
        for (int k = 0; k < 16; ++k) sums[base + k * 256 + tid] = 0.f;
    }
    if (rb == 48 && tid == 0) out[0] = 0.f;
}

// ---------------------------------------------------------------------------
// PERSISTENT symmetric MFMA pair kernel: 768 blocks (3/CU, pinned residency),
// grid-stride over the 2080 upper-tri tiles. Per-tile body is the r16-verified
// single-barrier 3-buffer ring verbatim (no cross-tile register state -> no
// spill). Cross-tile vmcnt safety: epilogue atomics are issued before the
// next tile's STAGE, so they are older in the in-order vmem queue and the
// next tile's counted waits are conservative-correct.
// ---------------------------------------------------------------------------
__global__ __launch_bounds__(256, 3) void pair_kernel(
    const _Float16* __restrict__ x16, const int* __restrict__ lbl,
    const float* __restrict__ sq,
    float* __restrict__ sum_same8, float* __restrict__ sum_all8) {

    __shared__ _Float16 As[3][TILE * BK];   // 24 KB
    __shared__ _Float16 Bs[3][TILE * BK];   // 24 KB

    const int tid  = threadIdx.x;
    const int w    = tid >> 6;
    const int lane = tid & 63;
    const int wm   = w >> 1;
    const int wn   = w & 1;
    const int cl   = lane & 15;
    const int g    = lane >> 4;

    // per-XCD partial arrays (xcd = blockIdx & 7 under round-robin dispatch)
    const int xcd = blockIdx.x & 7;
    float* __restrict__ sum_same = sum_same8 + (size_t)xcd * N;
    float* __restrict__ sum_all  = sum_all8  + (size_t)xcd * N;

    // staging chunk decode: 512 16B-chunks per tile; chunk c -> row=c>>2, kc=c&3
    const int c0 = w * 64 + lane;
    const int r0 = c0 >> 2, kc0 = c0 & 3;
    const int c1 = 256 + c0;
    const int r1 = c1 >> 2, kc1 = c1 & 3;

#define STAGE(buf, ibase, jbase, k0)                                            \
    do {                                                                        \
        load_lds16(x16 + (size_t)((ibase) + r0) * D + (k0) + kc0 * 8,           \
                   &As[buf][(size_t)(w * 64) * 8]);                             \
        load_lds16(x16 + (size_t)((jbase) + r0) * D + (k0) + kc0 * 8,           \
                   &Bs[buf][(size_t)(w * 64) * 8]);                             \
        load_lds16(x16 + (size_t)((ibase) + r1) * D + (k0) + kc1 * 8,           \
                   &As[buf][(size_t)(256 + w * 64) * 8]);                       \
        load_lds16(x16 + (size_t)((jbase) + r1) * D + (k0) + kc1 * 8,           \
                   &Bs[buf][(size_t)(256 + w * 64) * 8]);                       \
    } while (0)

    // ---- persistent grid-stride loop over tiles (wave-uniform) ----
    for (int tt = blockIdx.x; tt < NBLK; tt += PGRID) {
        // XCD-contiguous remap: blocks of one XCD sweep a contiguous tile range
        const int t = (tt & 7) * (NBLK / 8) + (tt >> 3);

        // decode upper-triangular block index: t -> (bi, bj), bi<=bj
        int bj = (int)((sqrtf(8.f * (float)t + 1.f) - 1.f) * 0.5f);
        while ((bj + 1) * (bj + 2) / 2 <= t) ++bj;
        while (bj * (bj + 1) / 2 > t) --bj;
        const int bi    = t - bj * (bj + 1) / 2;
        const bool diag = (bi == bj);
        const int i0 = bi * TILE;
        const int j0 = bj * TILE;

        const int rowbase = i0 + wm * 64;
        const int colbase = j0 + wn * 64;

        f32x4 acc[4][4];
#pragma unroll
        for (int a = 0; a < 4; ++a)
#pragma unroll
            for (int b = 0; b < 4; ++b) acc[a][b] = (f32x4){0.f, 0.f, 0.f, 0.f};

        STAGE(0, i0, j0, 0);       // prologue: stages 0 and 1 in flight
        STAGE(1, i0, j0, BK);

        float sqj_[4];
        int   yj_[4];

#pragma unroll
        for (int t8 = 0; t8 < 8; ++t8) {      // fully unrolled -> static %3
            const int cur = t8 % 3;

            // wait for tile t8 only: tile t8+1 (4 loads) stays in flight
            if (t8 < 7) asm volatile("s_waitcnt vmcnt(4)" ::: "memory");
            else        asm volatile("s_waitcnt vmcnt(0)" ::: "memory");
            __builtin_amdgcn_s_barrier();  // t8 landed AND buf (t8-1)%3 free

            // stage tile t8+2 into buf (t8+2)%3 == (t8-1)%3 — safe post-barrier
            if (t8 < 6) STAGE((t8 + 2) % 3, i0, j0, (t8 + 2) * BK);

            // last iter: issue epilogue operand loads; hide under MFMAs
            if (t8 == 7) {
#pragma unroll
                for (int nf = 0; nf < 4; ++nf) {
                    const int c = colbase + nf * 16 + cl;
                    sqj_[nf] = sq[c];
                    yj_[nf]  = lbl[c];
                }
            }

            half8 af[4], bf[4];
#pragma unroll
            for (int mf = 0; mf < 4; ++mf)
                af[mf] = *(const half8*)&As[cur][(wm * 64 + mf * 16 + cl) * BK + g * 8];
#pragma unroll
            for (int nf = 0; nf < 4; ++nf)
                bf[nf] = *(const half8*)&Bs[cur][(wn * 64 + nf * 16 + cl) * BK + g * 8];

            __builtin_amdgcn_s_setprio(1);
#pragma unroll
            for (int mf = 0; mf < 4; ++mf)
#pragma unroll
                for (int nf = 0; nf < 4; ++nf)
                    acc[mf][nf] = __builtin_amdgcn_mfma_f32_16x16x32_f16(
                        af[mf], bf[nf], acc[mf][nf], 0, 0, 0);
            __builtin_amdgcn_s_setprio(0);
            // no trailing barrier: next iter's leading barrier (or next tile's
            // first barrier) provides the consume-done guarantee.
        }

        // ---- epilogue (r7/r10-verified, two batches of 8 rows) ----
        // C layout (m89): col = lane&15, row = (lane>>4)*4 + reg
        float cs_all[4], cs_same[4];
#pragma unroll
        for (int nf = 0; nf < 4; ++nf) { cs_all[nf] = 0.f; cs_same[nf] = 0.f; }

#pragma unroll
        for (int b = 0; b < 2; ++b) {
            float rs_all[8], rs_same[8];
#pragma unroll
            for (int e = 0; e < 8; ++e) { rs_all[e] = 0.f; rs_same[e] = 0.f; }

#pragma unroll
            for (int mh = 0; mh < 2; ++mh) {
                const int mf = 2 * b + mh;
#pragma unroll
                for (int r = 0; r < 4; ++r) {
                    const int row   = rowbase + mf * 16 + g * 4 + r;
                    const float sqi = sq[row];
                    const int   yi  = lbl[row];
#pragma unroll
                    for (int nf = 0; nf < 4; ++nf) {
                        float d2   = sqi + sqj_[nf] - 2.f * acc[mf][nf][r];
                        float dist = __builtin_amdgcn_sqrtf(fmaxf(d2, EPS_F));
                        if (diag) {
                            const int col = colbase + nf * 16 + cl;
                            if (row == col) dist = 1e-5f;  // exact diag sqrt(EPS)
                        }
                        const float dm = (yi == yj_[nf]) ? dist : 0.f;
                        cs_all[nf] += dist;
                        cs_same[nf] += dm;
                        rs_all[mh * 4 + r] += dist;
                        rs_same[mh * 4 + r] += dm;
                    }
                }
            }

            // row direction (off-diag only): value-split 8 over 16 lanes +
            // closing mask-1 stage; even-cl lanes own entry e = cl>>1.
            if (!diag) {
#define RSTEP(h, mask, bit)                                                     \
                {                                                               \
                    const bool hi = (cl >> (bit)) & 1;                          \
                    _Pragma("unroll")                                           \
                    for (int j = 0; j < (h); ++j) {                             \
                        float sa_ = hi ? rs_all[j] : rs_all[j + (h)];           \
                        float ka_ = hi ? rs_all[j + (h)] : rs_all[j];           \
                        rs_all[j] = ka_ + __shfl_xor(sa_, (mask));              \
                        float ss_ = hi ? rs_same[j] : rs_same[j + (h)];         \
                        float ks_ = hi ? rs_same[j + (h)] : rs_same[j];         \
                        rs_same[j] = ks_ + __shfl_xor(ss_, (mask));             \
                    }                                                           \
                }
                RSTEP(4, 8, 3)
                RSTEP(2, 4, 2)
                RSTEP(1, 2, 1)
#undef RSTEP
                rs_all[0]  += __shfl_xor(rs_all[0], 1);   // closing stage
                rs_same[0] += __shfl_xor(rs_same[0], 1);

                const int e    = cl >> 1;
                const int rrow = rowbase + (2 * b + (e >> 2)) * 16 + g * 4 + (e & 3);
                if (!(cl & 1)) {
                    atomicAdd(&sum_all[rrow],  rs_all[0]);
                    atomicAdd(&sum_same[rrow], rs_same[0]);
                }
            }
        }

        // col direction: value-split reduce 4 values over 4 g-lanes
        {
            const bool hi1 = (g >> 1) & 1;
#pragma unroll
            for (int j = 0; j < 2; ++j) {
                float sa_ = hi1 ? cs_all[j] : cs_all[j + 2];
                float ka_ = hi1 ? cs_all[j + 2] : cs_all[j];
                cs_all[j] = ka_ + __shfl_xor(sa_, 32);
                float ss_ = hi1 ? cs_same[j] : cs_same[j + 2];
                float ks_ = hi1 ? cs_same[j + 2] : cs_same[j];
                cs_same[j] = ks_ + __shfl_xor(ss_, 32);
            }
            const bool hi0 = g & 1;
            {
                float sa_ = hi0 ? cs_all[0] : cs_all[1];
                float ka_ = hi0 ? cs_all[1] : cs_all[0];
                cs_all[0] = ka_ + __shfl_xor(sa_, 16);
                float ss_ = hi0 ? cs_same[0] : cs_same[1];
                float ks_ = hi0 ? cs_same[1] : cs_same[0];
                cs_same[0] = ks_ + __shfl_xor(ss_, 16);
            }
            const int ccol = colbase + g * 16 + cl;
            atomicAdd(&sum_all[ccol],  cs_all[0]);
            atomicAdd(&sum_same[ccol], cs_same[0]);
        }

        // barrier before next tile's STAGE overwrites buffers 0/1: all waves
        // must be done reading this tile's LDS (they are — the k-loop ended —
        // but waves may race ahead to the next tile's STAGE while a slower
        // wave is still in its epilogue ds-free section; epilogue touches no
        // LDS, yet STAGE writes buf 0/1 which iter-7 readers used. Fence it.)
        __builtin_amdgcn_s_barrier();
    }
#undef STAGE
}

// ---------------------------------------------------------------------------
// Finalize: 32 blocks x 256 thr, one row per thread (r16-verified verbatim).
// ---------------------------------------------------------------------------
__global__ void finalize_kernel(const float* __restrict__ sum_same8,
                                const float* __restrict__ sum_all8,
                                const int* __restrict__ lbl,
                                const int* __restrict__ hist16,
                                float* __restrict__ out) {
    __shared__ int lh[64];
    __shared__ float wsums[4];
    const int tid = threadIdx.x;
    if (tid < 64) {
        int h = 0;
#pragma unroll
        for (int b = 0; b < 16; ++b) h += hist16[b * 64 + tid];
        lh[tid] = h;
    }
    __syncthreads();

    const int row = blockIdx.x * 256 + tid;
    float ss = 0.f, sa = 0.f;
#pragma unroll
    for (int x = 0; x < 8; ++x) {
        ss += sum_same8[(size_t)x * N + row];
        sa += sum_all8[(size_t)x * N + row];
    }

    const float cnt = (float)lh[lbl[row]];
    const float ap  = ss / cnt;
    const float an  = (sa - ss) / ((float)N - cnt);
    float local = fmaxf(ap - an + MARGIN, 0.f);

#pragma unroll
    for (int off = 32; off > 0; off >>= 1) local += __shfl_down(local, off);
    const int lane = tid & 63, wave = tid >> 6;
    if (lane == 0) wsums[wave] = local;
    __syncthreads();
    if (tid == 0)
        atomicAdd(out, (wsums[0] + wsums[1] + wsums[2] + wsums[3]) / (float)N);
}

// ---------------------------------------------------------------------------
extern "C" void kernel_launch(void* const* d_in, const int* in_sizes, int n_in,
                              void* d_out, int out_size, void* d_ws, size_t ws_size,
                              hipStream_t stream) {
    const float* xs     = (const float*)d_in[0];
    const int*   ys_raw = (const int*)d_in[1];

    float* ws        = (float*)d_ws;
    float* sum_same8 = ws;                         // [8][N]
    float* sum_all8  = ws + 8 * N;                 // [8][N]
    float* sqv       = ws + 16 * N;                // [N]
    int*   lbl       = (int*)(ws + 17 * N);        // [N]
    int*   hist16    = (int*)(ws + 18 * N);        // [16*64]
    _Float16* x16    = (_Float16*)(ws + 18 * N + 1024);  // [N*D] fp16 (4 MB)

    prep_kernel<<<N / 16, 256, 0, stream>>>(xs, ys_raw, x16, sqv, lbl, hist16,
                                            sum_same8, (float*)d_out);

    pair_kernel<<<PGRID, 256, 0, stream>>>(x16, lbl, sqv, sum_same8, sum_all8);

    finalize_kernel<<<32, 256, 0, stream>>>(sum_same8, sum_all8, lbl, hist16,
                                            (float*)d_out);
}